// Round 1
// baseline (74.374 us; speedup 1.0000x reference)
//
#include <hip/hip_runtime.h>

#define BATCH   1024
#define IN_DIM  64
#define OUT_DIM 64
#define KORD    3
#define NKNOTS  23   // G + 2K + 1
#define NCOEF   19   // G + K

// One block per batch row b. Phase 1: threads 0..63 compute the 4 non-zero
// cubic B-spline bases for x[b][i] (degree-3 support is 4 wide) via the
// Cox-de Boor recursion restricted to the support — algebraically identical
// to the reference's full recursion because all other order-0 bases are 0.
// Phase 2: all 256 threads emit the 64x64 (o,i) output tile, 16 outputs each,
// coalesced over i. coeff reads are stride-19 gathers served by L1/L2
// (coeff is only 311 KB, fully cache-resident across all 1024 blocks).
__global__ __launch_bounds__(256) void spline_kernel(
    const float* __restrict__ x,
    const float* __restrict__ coeff,
    const float* __restrict__ grid,
    float* __restrict__ out)
{
    // padded to stride 5 so lanes i=0..63 reading sN[i][s] hit distinct banks
    __shared__ float sN[IN_DIM][5];
    __shared__ int   sJ[IN_DIM];

    const int b = blockIdx.x;
    const int t = threadIdx.x;

    if (t < IN_DIM) {
        const int i = t;
        const float xv = x[b * IN_DIM + i];
        // grid is (OUT, IN, NKNOTS) broadcast of the same knot vector;
        // use the o=0 row for this i.
        const float* tk = grid + i * NKNOTS;
        float kn[NKNOTS];
        #pragma unroll
        for (int m = 0; m < NKNOTS; ++m) kn[m] = tk[m];

        // order-0: find interval j with kn[j] <= x < kn[j+1] (same half-open
        // comparisons as the reference init)
        int j = -1;
        #pragma unroll
        for (int m = 0; m < NKNOTS - 1; ++m)
            if (xv >= kn[m] && xv < kn[m + 1]) j = m;

        float N[4] = {0.f, 0.f, 0.f, 0.f};
        int jj = 0;
        if (j >= 0) {
            // x in [0,1) guarantees j in [3,18]; clamp for safety only
            if (j < KORD) j = KORD;
            if (j > NKNOTS - 2 - KORD) j = NKNOTS - 2 - KORD;
            N[0] = 1.f;  // B_j^0
            // after level p: N[s] = B_{j-p+s}^p, s = 0..p
            #pragma unroll
            for (int p = 1; p <= KORD; ++p) {
                #pragma unroll
                for (int s = KORD; s >= 0; --s) {
                    if (s > p) continue;
                    const int m = j - p + s;
                    const float left  = (s >= 1)     ? N[s - 1] : 0.f;
                    const float right = (s <= p - 1) ? N[s]     : 0.f;
                    const float a = (xv - kn[m])         / (kn[m + p]     - kn[m]);
                    const float c = (kn[m + p + 1] - xv) / (kn[m + p + 1] - kn[m + 1]);
                    N[s] = a * left + c * right;
                }
            }
            jj = j - KORD;  // first non-zero coefficient index, in [0, NCOEF-4]
        }
        sN[i][0] = N[0];
        sN[i][1] = N[1];
        sN[i][2] = N[2];
        sN[i][3] = N[3];
        sJ[i] = jj;
    }
    __syncthreads();

    // Phase 2: t -> (i = t&63 fast axis for coalesced stores, og = t>>6)
    const int i  = t & 63;
    const int og = t >> 6;             // 0..3, each covers 16 o's
    const int jj = sJ[i];
    const float n0 = sN[i][0];
    const float n1 = sN[i][1];
    const float n2 = sN[i][2];
    const float n3 = sN[i][3];

    float* __restrict__ outb = out + (size_t)b * (OUT_DIM * IN_DIM);
    #pragma unroll
    for (int r = 0; r < 16; ++r) {
        const int o = og * 16 + r;
        const float* __restrict__ cp = coeff + ((size_t)o * IN_DIM + i) * NCOEF + jj;
        const float v = n0 * cp[0] + n1 * cp[1] + n2 * cp[2] + n3 * cp[3];
        outb[o * IN_DIM + i] = v;
    }
}

extern "C" void kernel_launch(void* const* d_in, const int* in_sizes, int n_in,
                              void* d_out, int out_size, void* d_ws, size_t ws_size,
                              hipStream_t stream) {
    const float* x     = (const float*)d_in[0];  // (1024, 64)
    const float* coeff = (const float*)d_in[1];  // (64, 64, 19)
    const float* grid  = (const float*)d_in[2];  // (64, 64, 23)
    float* out = (float*)d_out;                  // (1024, 64, 64)

    spline_kernel<<<BATCH, 256, 0, stream>>>(x, coeff, grid, out);
}